// Round 7
// baseline (303.479 us; speedup 1.0000x reference)
//
#include <hip/hip_runtime.h>
#include <hip/hip_bf16.h>

// Problem shapes (fixed by setup_inputs)
constexpr int B_  = 4;
constexpr int N_  = 2048;
constexpr int C_  = 1024;
constexpr int H_  = 16;
constexpr int HD  = 64;    // head dim
constexpr int LR  = 20;    // low rank
constexpr int RS  = 200;   // subsample length R
constexpr int RP  = 224;   // RS padded to multiple of 32 (zero-filled)

typedef __attribute__((ext_vector_type(8))) short bf16x8;
typedef __attribute__((ext_vector_type(4))) float f32x4;

__device__ __forceinline__ float b2f_raw(unsigned short u) {
    union { unsigned int i; float f; } v;
    v.i = ((unsigned int)u) << 16;
    return v.f;
}
__device__ __forceinline__ unsigned short f2b(float f) {
    __hip_bfloat16 h = __float2bfloat16(f);
    return *(unsigned short*)&h;
}
template <bool BF>
__device__ __forceinline__ float ldg(const void* p, size_t i) {
    if constexpr (BF) return b2f_raw(((const unsigned short*)p)[i]);
    else              return ((const float*)p)[i];
}

// ---------------------------------------------------------------------------
// Inline dtype detect (deterministic function of x[0..1023]; all blocks in
// all kernels agree). Wave-uniform; ~4KB L2-hot read.
// ---------------------------------------------------------------------------
__device__ __forceinline__ bool detect_bf16(const unsigned int* __restrict__ x) {
    const int lane = threadIdx.x & 63;
    int cnt = 0;
    #pragma unroll
    for (int i = 0; i < 16; ++i) {
        const unsigned int w = x[lane * 16 + i];
        const unsigned int e = (w >> 7) & 0xFFu;
        cnt += (e >= 103u && e <= 140u) ? 1 : 0;
    }
    #pragma unroll
    for (int s = 1; s < 64; s <<= 1) cnt += __shfl_xor(cnt, s, 64);
    return cnt > 512;
}

// ---------------------------------------------------------------------------
// Fused prep (unchanged from round 6 — verified). Grid (2048, 3):
//  y == 0: convert x (fp32->bf16, float4; skipped when bf16)
//  y == 1: convert qkw/proj_w/proj_b/cw_b, flattened (skipped when bf16)
//  y == 2: blocks 0..895 -> wec; 896..1023 -> gather via LDS transpose.
// ---------------------------------------------------------------------------
struct CvtArgs {
    const void* src[5];
    unsigned short* dst[5];
    int size[5];
};

template <bool BF>
__device__ void wec_body(const void* __restrict__ we_raw,
                         const void* __restrict__ wr_raw,
                         const void* __restrict__ cw_raw,
                         unsigned short* __restrict__ wect,
                         unsigned short* __restrict__ wrct) {
    const int o = blockIdx.x * 256 + threadIdx.x;
    if (o >= H_ * HD * RP) return;
    const int r    = o % RP;
    const int dout = (o / RP) % HD;
    const int h    = o / (RP * HD);
    float sq = 0.f, sk = 0.f;
    if (r < RS) {
        #pragma unroll
        for (int e = 0; e < LR; ++e) {
            const float cq = ldg<BF>(cw_raw, dout * 2 * LR + e);
            const float ck = ldg<BF>(cw_raw, dout * 2 * LR + LR + e);
            sq += ldg<BF>(we_raw, ((size_t)h * RS + r) * LR + e) * cq;
            sk += ldg<BF>(wr_raw, ((size_t)h * RS + r) * LR + e) * ck;
        }
    }
    wect[o] = f2b(sq);
    wrct[o] = f2b(sk);
}

template <bool BF>
__device__ void gather_lds_body(const void* __restrict__ x_raw,
                                unsigned short* __restrict__ xh,
                                unsigned short* __restrict__ sx,  // [224*32]
                                int g) {
    const int bh    = g >> 1;
    const int dhalf = g & 1;
    const int b = bh >> 4;
    const int h = bh & 15;
    const int t    = threadIdx.x;
    const int wave = t >> 6;
    const int lane = t & 63;
    const int dlo = lane & 31;
    const int rhi = lane >> 5;     // 0/1
    for (int rd = wave; rd < 100; rd += 4) {
        const int r  = rd * 2 + rhi;
        const int ir = (r * (N_ - 1)) / (RS - 1);
        const size_t idx = ((size_t)b * N_ + ir) * C_ + h * HD + dhalf * 32 + dlo;
        unsigned short v;
        if constexpr (BF) v = ((const unsigned short*)x_raw)[idx];
        else              v = f2b(((const float*)x_raw)[idx]);
        sx[r * 32 + (dlo ^ (r & 31))] = v;
    }
    __syncthreads();
    for (int o = t; o < 32 * 224; o += 256) {
        const int din = o / 224;   // within-half din
        const int r   = o % 224;
        const unsigned short v = (r < RS) ? sx[r * 32 + (din ^ (r & 31))]
                                          : (unsigned short)0;
        xh[(size_t)bh * HD * RP + (size_t)(dhalf * 32 + din) * RP + r] = v;
    }
}

__global__ __launch_bounds__(256)
void fused_prep_kernel(CvtArgs args,
                       const void* __restrict__ we_raw,
                       const void* __restrict__ wr_raw,
                       const void* __restrict__ cw_raw,
                       unsigned short* __restrict__ wect,
                       unsigned short* __restrict__ wrct,
                       unsigned short* __restrict__ xh) {
    __shared__ unsigned short sx[224 * 32];   // gather transpose buffer (14KB)
    const bool isbf = detect_bf16((const unsigned int*)args.src[0]);
    const int y = blockIdx.y;
    if (y == 0) {
        if (isbf) return;   // zero-copy: consumers read raw bf16 directly
        const int n4 = args.size[0] >> 2;
        const int stride = 2048 * 256;
        for (int i = blockIdx.x * 256 + threadIdx.x; i < n4; i += stride) {
            const float4 v = ((const float4*)args.src[0])[i];
            ushort4 o;
            o.x = f2b(v.x); o.y = f2b(v.y); o.z = f2b(v.z); o.w = f2b(v.w);
            ((ushort4*)args.dst[0])[i] = o;
        }
    } else if (y == 1) {
        if (isbf) return;
        const int n1 = args.size[1] >> 2;
        const int n2 = args.size[2] >> 2;
        const int n3 = args.size[3] >> 2;
        const int n4 = args.size[4] >> 2;
        const int tot = n1 + n2 + n3 + n4;
        const int stride = 2048 * 256;
        for (int i = blockIdx.x * 256 + threadIdx.x; i < tot; i += stride) {
            const float4* s; ushort4* d; int j;
            if (i < n1)                { s = (const float4*)args.src[1]; d = (ushort4*)args.dst[1]; j = i; }
            else if (i < n1 + n2)      { s = (const float4*)args.src[2]; d = (ushort4*)args.dst[2]; j = i - n1; }
            else if (i < n1 + n2 + n3) { s = (const float4*)args.src[3]; d = (ushort4*)args.dst[3]; j = i - n1 - n2; }
            else                       { s = (const float4*)args.src[4]; d = (ushort4*)args.dst[4]; j = i - n1 - n2 - n3; }
            const float4 v = s[j];
            ushort4 o;
            o.x = f2b(v.x); o.y = f2b(v.y); o.z = f2b(v.z); o.w = f2b(v.w);
            d[j] = o;
        }
    } else {
        const int blk = blockIdx.x;
        if (blk < 896) {
            if (isbf) wec_body<true>(we_raw, wr_raw, cw_raw, wect, wrct);
            else      wec_body<false>(we_raw, wr_raw, cw_raw, wect, wrct);
        } else if (blk < 1024) {
            const int g = blk - 896;
            if (isbf) gather_lds_body<true>(args.src[0], xh, sx, g);
            else      gather_lds_body<false>(args.src[0], xh, sx, g);
        }
    }
}

// ---------------------------------------------------------------------------
// collapse (unchanged — verified).
// ---------------------------------------------------------------------------
__global__ __launch_bounds__(64)
void collapse_kernel(const unsigned short* __restrict__ xh,
                     const unsigned short* __restrict__ wect,
                     const unsigned short* __restrict__ wrct,
                     unsigned short* __restrict__ we2t,
                     unsigned short* __restrict__ wr2t) {
    const int blk = blockIdx.x;
    const int bh  = blk >> 2;
    const int qk  = (blk >> 1) & 1;
    const int dh  = blk & 1;
    const int h   = bh & 15;
    const int lane = threadIdx.x;
    const int lq = lane >> 4;
    const int lm = lane & 15;

    const unsigned short* wsrc = (qk ? wrct : wect) + (size_t)h * HD * RP;
    const unsigned short* xsrc = xh + (size_t)bh * HD * RP;
    unsigned short* dst = (qk ? wr2t : we2t) + (size_t)bh * HD * HD;

    f32x4 acc[2][4];
    #pragma unroll
    for (int i = 0; i < 2; ++i)
        #pragma unroll
        for (int j = 0; j < 4; ++j) acc[i][j] = 0.f;

    for (int ks = 0; ks < RP / 32; ++ks) {
        bf16x8 a[2], bfr[4];
        #pragma unroll
        for (int rt = 0; rt < 2; ++rt)
            a[rt] = *(const bf16x8*)&wsrc[(size_t)(dh * 32 + rt * 16 + lm) * RP + ks * 32 + lq * 8];
        #pragma unroll
        for (int j = 0; j < 4; ++j)
            bfr[j] = *(const bf16x8*)&xsrc[(size_t)(j * 16 + lm) * RP + ks * 32 + lq * 8];
        #pragma unroll
        for (int rt = 0; rt < 2; ++rt)
            #pragma unroll
            for (int j = 0; j < 4; ++j)
                acc[rt][j] = __builtin_amdgcn_mfma_f32_16x16x32_bf16(
                    a[rt], bfr[j], acc[rt][j], 0, 0, 0);
    }

    #pragma unroll
    for (int rt = 0; rt < 2; ++rt)
        #pragma unroll
        for (int j = 0; j < 4; ++j)
            #pragma unroll
            for (int r = 0; r < 4; ++r) {
                const int dout = dh * 32 + rt * 16 + lq * 4 + r;
                const int din  = j * 16 + lm;
                dst[dout * HD + din] = f2b(acc[rt][j][r]);
            }
}

// ---------------------------------------------------------------------------
// Fused gemm1 + l2norm + score. NEW this round: barrier-free K-loop.
// MFMA fragments are loaded per-lane DIRECTLY from global (flatmm pattern):
// each lane's A-frag is a contiguous 16B at row(m0+wr+i*16+lm), col k+lq*8.
// No LDS, no __syncthreads, no staging in the K-loop — the 2-phase barrier
// drain (the measured ~72% stall, m233) is eliminated rather than amortized.
// Operand panels are L2-resident (XCD swizzle keeps per-XCD working set
// ~2.3MB < 4MB L2); wave pairs read identical fragments -> L1 hits.
// Software prefetch one 32-step ahead (a0/b0 <-> a1/b1 register sets).
// k-monotonic accumulation order == previous ks=0,1 order -> bit-identical.
// LDS now only qn/kn (36KB) for the l2norm/score epilogue.
// ---------------------------------------------------------------------------
__global__ __launch_bounds__(256, 2)
void gemm1_score_kernel(const void* __restrict__ x_raw,
                        const void* __restrict__ qkw_raw,
                        const void* __restrict__ cwb_raw,
                        const unsigned short* __restrict__ xb,
                        const unsigned short* __restrict__ qkwb,
                        const unsigned short* __restrict__ cwbb,
                        const unsigned short* __restrict__ we2t,
                        const unsigned short* __restrict__ wr2t,
                        unsigned short* __restrict__ attn) {
    constexpr int QS = 72;
    __shared__ __align__(16) unsigned short pool[2 * 128 * QS];  // 36 KB
    unsigned short* qn = pool;                    // 128xQS
    unsigned short* kn = pool + 128 * QS;

    const bool isbf = detect_bf16((const unsigned int*)x_raw);
    const unsigned short* xs  = isbf ? (const unsigned short*)x_raw   : xb;
    const unsigned short* qks = isbf ? (const unsigned short*)qkw_raw : qkwb;
    const unsigned short* cwb = isbf ? (const unsigned short*)cwb_raw : cwbb;

    const int t    = threadIdx.x;
    const int wave = t >> 6;
    const int lane = t & 63;
    // XCD-chunked bijective swizzle (1024 blocks, 128 per XCD)
    const int lin     = blockIdx.y * 16 + blockIdx.x;
    const int logical = (lin & 7) * 128 + (lin >> 3);
    const int h       = logical & 15;
    const int mt      = logical >> 4;       // m-tile 0..63
    const int m0      = mt * 128;

    const int wr = (wave >> 1) * 64;        // row quadrant
    const int wc = (wave & 1) * 64;         // col quadrant: 0 = q, 64 = k
    const int lq = lane >> 4;
    const int lm = lane & 15;

    // per-lane fragment base pointers (16B contiguous per load)
    const unsigned short* Abase = xs + (size_t)(m0 + wr + lm) * C_ + lq * 8;
    const size_t brow0 = (wc == 0) ? (size_t)(h * HD) : (size_t)(C_ + h * HD);
    const unsigned short* Bbase = qks + (brow0 + lm) * C_ + lq * 8;

    f32x4 acc[4][4];
    #pragma unroll
    for (int i = 0; i < 4; ++i)
        #pragma unroll
        for (int j = 0; j < 4; ++j) acc[i][j] = 0.f;

    auto ldA = [&](bf16x8* f, int k) {
        #pragma unroll
        for (int i = 0; i < 4; ++i)
            f[i] = *(const bf16x8*)(Abase + (size_t)i * 16 * C_ + k);
    };
    auto ldB = [&](bf16x8* f, int k) {
        #pragma unroll
        for (int j = 0; j < 4; ++j)
            f[j] = *(const bf16x8*)(Bbase + (size_t)j * 16 * C_ + k);
    };
    auto mm = [&](const bf16x8* a, const bf16x8* b) {
        #pragma unroll
        for (int i = 0; i < 4; ++i)
            #pragma unroll
            for (int j = 0; j < 4; ++j)
                acc[i][j] = __builtin_amdgcn_mfma_f32_16x16x32_bf16(
                    a[i], b[j], acc[i][j], 0, 0, 0);
    };

    bf16x8 a0[4], b0[4], a1[4], b1[4];
    ldA(a0, 0); ldB(b0, 0);
    #pragma unroll 1
    for (int k = 0; k < C_ - 64; k += 64) {
        ldA(a1, k + 32); ldB(b1, k + 32);   // prefetch under mm(a0,b0)
        mm(a0, b0);
        ldA(a0, k + 64); ldB(b0, k + 64);   // prefetch under mm(a1,b1)
        mm(a1, b1);
    }
    ldA(a1, C_ - 32); ldB(b1, C_ - 32);
    mm(a0, b0);
    mm(a1, b1);

    // ---- phase 2a: per-row l2 norm + scaled bf16 store to LDS ----
    unsigned short* dst = (wc == 0) ? qn : kn;
    #pragma unroll
    for (int i = 0; i < 4; ++i) {
        float inv[4];
        #pragma unroll
        for (int r = 0; r < 4; ++r) {
            float s = 0.f;
            #pragma unroll
            for (int j = 0; j < 4; ++j) s += acc[i][j][r] * acc[i][j][r];
            s += __shfl_xor(s, 1, 64);
            s += __shfl_xor(s, 2, 64);
            s += __shfl_xor(s, 4, 64);
            s += __shfl_xor(s, 8, 64);
            inv[r] = 1.f / fmaxf(sqrtf(s), 1e-12f);
        }
        #pragma unroll
        for (int j = 0; j < 4; ++j)
            #pragma unroll
            for (int r = 0; r < 4; ++r) {
                const int row = wr + i * 16 + lq * 4 + r;
                dst[row * QS + j * 16 + lm] = f2b(acc[i][j][r] * inv[r]);
            }
    }
    __syncthreads();

    // ---- phase 2b: attn = qn@We2T^T + kn@Wr2T^T + cw_b ----
    const int b  = mt >> 4;
    const int bh = b * H_ + h;
    const unsigned short* wq = we2t + (size_t)bh * HD * HD;
    const unsigned short* wk = wr2t + (size_t)bh * HD * HD;

    bf16x8 bq[2][4], bk[2][4];
    #pragma unroll
    for (int t2 = 0; t2 < 2; ++t2)
        #pragma unroll
        for (int j = 0; j < 4; ++j) {
            const int dout = j * 16 + lm;
            bq[t2][j] = *(const bf16x8*)&wq[dout * HD + t2 * 32 + lq * 8];
            bk[t2][j] = *(const bf16x8*)&wk[dout * HD + t2 * 32 + lq * 8];
        }

    f32x4 accS[2][4];
    #pragma unroll
    for (int rt = 0; rt < 2; ++rt)
        #pragma unroll
        for (int j = 0; j < 4; ++j) accS[rt][j] = 0.f;

    #pragma unroll
    for (int rt = 0; rt < 2; ++rt) {
        const int lr = wave * 32 + rt * 16 + lm;
        bf16x8 aq0 = *(const bf16x8*)&qn[lr * QS + lq * 8];
        bf16x8 aq1 = *(const bf16x8*)&qn[lr * QS + 32 + lq * 8];
        bf16x8 ak0 = *(const bf16x8*)&kn[lr * QS + lq * 8];
        bf16x8 ak1 = *(const bf16x8*)&kn[lr * QS + 32 + lq * 8];
        #pragma unroll
        for (int j = 0; j < 4; ++j) {
            accS[rt][j] = __builtin_amdgcn_mfma_f32_16x16x32_bf16(aq0, bq[0][j], accS[rt][j], 0, 0, 0);
            accS[rt][j] = __builtin_amdgcn_mfma_f32_16x16x32_bf16(aq1, bq[1][j], accS[rt][j], 0, 0, 0);
            accS[rt][j] = __builtin_amdgcn_mfma_f32_16x16x32_bf16(ak0, bk[0][j], accS[rt][j], 0, 0, 0);
            accS[rt][j] = __builtin_amdgcn_mfma_f32_16x16x32_bf16(ak1, bk[1][j], accS[rt][j], 0, 0, 0);
        }
    }

    #pragma unroll
    for (int rt = 0; rt < 2; ++rt)
        #pragma unroll
        for (int j = 0; j < 4; ++j) {
            const int dout = j * 16 + lm;
            const float bv = b2f_raw(cwb[dout]);
            #pragma unroll
            for (int r = 0; r < 4; ++r) {
                const int row = m0 + wave * 32 + rt * 16 + lq * 4 + r;
                attn[(size_t)row * C_ + h * HD + dout] = f2b(accS[rt][j][r] + bv);
            }
        }
}

// ---------------------------------------------------------------------------
// Output projection: same barrier-free direct-fragment K-loop. Zero LDS.
// ---------------------------------------------------------------------------
template <bool OBF>
__device__ void mfma_gemm_frag(const unsigned short* __restrict__ A,
                               const unsigned short* __restrict__ W,
                               const unsigned short* __restrict__ bias,
                               void* __restrict__ out,
                               int N, int K, int m0, int n0) {
    const int t    = threadIdx.x;
    const int wave = t >> 6;
    const int lane = t & 63;

    const int wr = (wave >> 1) * 64;
    const int wc = (wave & 1) * 64;
    const int lq = lane >> 4;
    const int lm = lane & 15;

    const unsigned short* Abase = A + (size_t)(m0 + wr + lm) * K + lq * 8;
    const unsigned short* Bbase = W + (size_t)(n0 + wc + lm) * K + lq * 8;

    f32x4 acc[4][4];
    #pragma unroll
    for (int i = 0; i < 4; ++i)
        #pragma unroll
        for (int j = 0; j < 4; ++j) acc[i][j] = 0.f;

    auto ldA = [&](bf16x8* f, int k) {
        #pragma unroll
        for (int i = 0; i < 4; ++i)
            f[i] = *(const bf16x8*)(Abase + (size_t)i * 16 * K + k);
    };
    auto ldB = [&](bf16x8* f, int k) {
        #pragma unroll
        for (int j = 0; j < 4; ++j)
            f[j] = *(const bf16x8*)(Bbase + (size_t)j * 16 * K + k);
    };
    auto mm = [&](const bf16x8* a, const bf16x8* b) {
        #pragma unroll
        for (int i = 0; i < 4; ++i)
            #pragma unroll
            for (int j = 0; j < 4; ++j)
                acc[i][j] = __builtin_amdgcn_mfma_f32_16x16x32_bf16(
                    a[i], b[j], acc[i][j], 0, 0, 0);
    };

    bf16x8 a0[4], b0[4], a1[4], b1[4];
    ldA(a0, 0); ldB(b0, 0);
    #pragma unroll 1
    for (int k = 0; k < 1024 - 64; k += 64) {
        ldA(a1, k + 32); ldB(b1, k + 32);
        mm(a0, b0);
        ldA(a0, k + 64); ldB(b0, k + 64);
        mm(a1, b1);
    }
    ldA(a1, 1024 - 32); ldB(b1, 1024 - 32);
    mm(a0, b0);
    mm(a1, b1);

    #pragma unroll
    for (int i = 0; i < 4; ++i) {
        #pragma unroll
        for (int j = 0; j < 4; ++j) {
            const int col = n0 + wc + j * 16 + lm;
            const float bv = b2f_raw(bias[col]);
            #pragma unroll
            for (int r = 0; r < 4; ++r) {
                const int row = m0 + wr + i * 16 + lq * 4 + r;
                const float v = acc[i][j][r] + bv;
                if constexpr (OBF)
                    ((__hip_bfloat16*)out)[(size_t)row * N + col] = __float2bfloat16(v);
                else
                    ((float*)out)[(size_t)row * N + col] = v;
            }
        }
    }
}

__global__ __launch_bounds__(256, 2)
void gemm2_kernel(const void* __restrict__ x_raw,
                  const void* __restrict__ pw_raw,
                  const void* __restrict__ pb_raw,
                  const unsigned short* __restrict__ attn,
                  const unsigned short* __restrict__ pwb,
                  const unsigned short* __restrict__ pbb,
                  void* __restrict__ out) {
    const bool isbf = detect_bf16((const unsigned int*)x_raw);
    const unsigned short* W = isbf ? (const unsigned short*)pw_raw : pwb;
    const unsigned short* bias = isbf ? (const unsigned short*)pb_raw : pbb;
    // XCD-chunked bijective swizzle (512 blocks, 64 per XCD)
    const int lin     = blockIdx.y * 8 + blockIdx.x;
    const int logical = (lin & 7) * 64 + (lin >> 3);
    const int n0      = (logical & 7) * 128;
    const int m0      = (logical >> 3) * 128;
    if (isbf) mfma_gemm_frag<true>(attn, W, bias, out, C_, C_, m0, n0);
    else      mfma_gemm_frag<false>(attn, W, bias, out, C_, C_, m0, n0);
}

// ---------------------------------------------------------------------------
// 4 dispatches: prep(convert+wec+gather) -> collapse -> gemm1_score -> gemm2.
// ws high-water ~44 MB (< proven-safe 57.9 MB).
// ---------------------------------------------------------------------------
extern "C" void kernel_launch(void* const* d_in, const int* in_sizes, int n_in,
                              void* d_out, int out_size, void* d_ws, size_t ws_size,
                              hipStream_t stream) {
    (void)in_sizes; (void)n_in; (void)out_size; (void)ws_size;

    char* ws = (char*)d_ws;
    size_t off = 0;
    auto alloc = [&](size_t bytes) {
        char* p = ws + off;
        off += (bytes + 255) & ~(size_t)255;
        return p;
    };

    unsigned short* xb    = (unsigned short*)alloc((size_t)B_ * N_ * C_ * 2);   // 16.78 MB
    unsigned short* qkwb  = (unsigned short*)alloc((size_t)2 * C_ * C_ * 2);    // 4.19 MB
    unsigned short* pwb   = (unsigned short*)alloc((size_t)C_ * C_ * 2);        // 2.10 MB
    unsigned short* pbb   = (unsigned short*)alloc((size_t)C_ * 2);
    unsigned short* cwbb  = (unsigned short*)alloc((size_t)HD * 2);
    unsigned short* attn  = (unsigned short*)alloc((size_t)B_ * N_ * C_ * 2);   // 16.78 MB
    unsigned short* we2t  = (unsigned short*)alloc((size_t)B_ * H_ * HD * HD * 2);
    unsigned short* wr2t  = (unsigned short*)alloc((size_t)B_ * H_ * HD * HD * 2);
    unsigned short* wect  = (unsigned short*)alloc((size_t)H_ * HD * RP * 2);
    unsigned short* wrct  = (unsigned short*)alloc((size_t)H_ * HD * RP * 2);
    unsigned short* xh    = (unsigned short*)alloc((size_t)B_ * H_ * HD * RP * 2);

    const int M = B_ * N_;  // 8192

    // 1) prep: converts (skipped for bf16) + wec + gather
    CvtArgs ca;
    ca.src[0] = d_in[0]; ca.dst[0] = xb;   ca.size[0] = B_ * N_ * C_;
    ca.src[1] = d_in[1]; ca.dst[1] = qkwb; ca.size[1] = 2 * C_ * C_;
    ca.src[2] = d_in[2]; ca.dst[2] = pwb;  ca.size[2] = C_ * C_;
    ca.src[3] = d_in[3]; ca.dst[3] = pbb;  ca.size[3] = C_;
    ca.src[4] = d_in[7]; ca.dst[4] = cwbb; ca.size[4] = HD;
    fused_prep_kernel<<<dim3(2048, 3), 256, 0, stream>>>(
        ca, d_in[4], d_in[5], d_in[6], wect, wrct, xh);

    // 2) collapse -> We2T/Wr2T
    collapse_kernel<<<B_ * H_ * 4, 64, 0, stream>>>(xh, wect, wrct, we2t, wr2t);

    // 3) fused qk-projection + l2norm + score -> attn
    gemm1_score_kernel<<<dim3(16, M / 128), 256, 0, stream>>>(
        d_in[0], d_in[1], d_in[7], xb, qkwb, cwbb, we2t, wr2t, attn);

    // 4) output projection: out = attn @ proj_w^T + proj_b
    gemm2_kernel<<<dim3(C_ / 128, M / 128), 256, 0, stream>>>(
        d_in[0], d_in[2], d_in[3], attn, pwb, pbb, d_out);
}

// Round 9
// 210.566 us; speedup vs baseline: 1.4413x; 1.4413x over previous
//
#include <hip/hip_runtime.h>
#include <hip/hip_bf16.h>

// Problem shapes (fixed by setup_inputs)
constexpr int B_  = 4;
constexpr int N_  = 2048;
constexpr int C_  = 1024;
constexpr int H_  = 16;
constexpr int HD  = 64;    // head dim
constexpr int LR  = 20;    // low rank
constexpr int RS  = 200;   // subsample length R
constexpr int RP  = 224;   // RS padded to multiple of 32 (zero-filled)

typedef __attribute__((ext_vector_type(8))) short bf16x8;
typedef __attribute__((ext_vector_type(4))) float f32x4;

__device__ __forceinline__ float b2f_raw(unsigned short u) {
    union { unsigned int i; float f; } v;
    v.i = ((unsigned int)u) << 16;
    return v.f;
}
__device__ __forceinline__ unsigned short f2b(float f) {
    __hip_bfloat16 h = __float2bfloat16(f);
    return *(unsigned short*)&h;
}
template <bool BF>
__device__ __forceinline__ float ldg(const void* p, size_t i) {
    if constexpr (BF) return b2f_raw(((const unsigned short*)p)[i]);
    else              return ((const float*)p)[i];
}

// async 16B global->LDS (wave-uniform LDS base; HW scatters lane i at +16*i)
__device__ __forceinline__ void async_load16(const unsigned short* g, unsigned short* l) {
    __builtin_amdgcn_global_load_lds(
        (const __attribute__((address_space(1))) unsigned int*)(const void*)g,
        (__attribute__((address_space(3))) unsigned int*)(void*)l,
        16, 0, 0);
}

// ---------------------------------------------------------------------------
// Inline dtype detect (deterministic function of x[0..1023]; all blocks in
// all kernels agree). Wave-uniform; ~4KB L2-hot read.
// ---------------------------------------------------------------------------
__device__ __forceinline__ bool detect_bf16(const unsigned int* __restrict__ x) {
    const int lane = threadIdx.x & 63;
    int cnt = 0;
    #pragma unroll
    for (int i = 0; i < 16; ++i) {
        const unsigned int w = x[lane * 16 + i];
        const unsigned int e = (w >> 7) & 0xFFu;
        cnt += (e >= 103u && e <= 140u) ? 1 : 0;
    }
    #pragma unroll
    for (int s = 1; s < 64; s <<= 1) cnt += __shfl_xor(cnt, s, 64);
    return cnt > 512;
}

// ---------------------------------------------------------------------------
// Fused prep (unchanged from round 6 — verified). Grid (2048, 3):
//  y == 0: convert x (fp32->bf16, float4; skipped when bf16)
//  y == 1: convert qkw/proj_w/proj_b/cw_b, flattened (skipped when bf16)
//  y == 2: blocks 0..895 -> wec; 896..1023 -> gather via LDS transpose.
// ---------------------------------------------------------------------------
struct CvtArgs {
    const void* src[5];
    unsigned short* dst[5];
    int size[5];
};

template <bool BF>
__device__ void wec_body(const void* __restrict__ we_raw,
                         const void* __restrict__ wr_raw,
                         const void* __restrict__ cw_raw,
                         unsigned short* __restrict__ wect,
                         unsigned short* __restrict__ wrct) {
    const int o = blockIdx.x * 256 + threadIdx.x;
    if (o >= H_ * HD * RP) return;
    const int r    = o % RP;
    const int dout = (o / RP) % HD;
    const int h    = o / (RP * HD);
    float sq = 0.f, sk = 0.f;
    if (r < RS) {
        #pragma unroll
        for (int e = 0; e < LR; ++e) {
            const float cq = ldg<BF>(cw_raw, dout * 2 * LR + e);
            const float ck = ldg<BF>(cw_raw, dout * 2 * LR + LR + e);
            sq += ldg<BF>(we_raw, ((size_t)h * RS + r) * LR + e) * cq;
            sk += ldg<BF>(wr_raw, ((size_t)h * RS + r) * LR + e) * ck;
        }
    }
    wect[o] = f2b(sq);
    wrct[o] = f2b(sk);
}

template <bool BF>
__device__ void gather_lds_body(const void* __restrict__ x_raw,
                                unsigned short* __restrict__ xh,
                                unsigned short* __restrict__ sx,  // [224*32]
                                int g) {
    const int bh    = g >> 1;
    const int dhalf = g & 1;
    const int b = bh >> 4;
    const int h = bh & 15;
    const int t    = threadIdx.x;
    const int wave = t >> 6;
    const int lane = t & 63;
    const int dlo = lane & 31;
    const int rhi = lane >> 5;     // 0/1
    for (int rd = wave; rd < 100; rd += 4) {
        const int r  = rd * 2 + rhi;
        const int ir = (r * (N_ - 1)) / (RS - 1);
        const size_t idx = ((size_t)b * N_ + ir) * C_ + h * HD + dhalf * 32 + dlo;
        unsigned short v;
        if constexpr (BF) v = ((const unsigned short*)x_raw)[idx];
        else              v = f2b(((const float*)x_raw)[idx]);
        sx[r * 32 + (dlo ^ (r & 31))] = v;
    }
    __syncthreads();
    for (int o = t; o < 32 * 224; o += 256) {
        const int din = o / 224;   // within-half din
        const int r   = o % 224;
        const unsigned short v = (r < RS) ? sx[r * 32 + (din ^ (r & 31))]
                                          : (unsigned short)0;
        xh[(size_t)bh * HD * RP + (size_t)(dhalf * 32 + din) * RP + r] = v;
    }
}

__global__ __launch_bounds__(256)
void fused_prep_kernel(CvtArgs args,
                       const void* __restrict__ we_raw,
                       const void* __restrict__ wr_raw,
                       const void* __restrict__ cw_raw,
                       unsigned short* __restrict__ wect,
                       unsigned short* __restrict__ wrct,
                       unsigned short* __restrict__ xh) {
    __shared__ unsigned short sx[224 * 32];   // gather transpose buffer (14KB)
    const bool isbf = detect_bf16((const unsigned int*)args.src[0]);
    const int y = blockIdx.y;
    if (y == 0) {
        if (isbf) return;   // zero-copy: consumers read raw bf16 directly
        const int n4 = args.size[0] >> 2;
        const int stride = 2048 * 256;
        for (int i = blockIdx.x * 256 + threadIdx.x; i < n4; i += stride) {
            const float4 v = ((const float4*)args.src[0])[i];
            ushort4 o;
            o.x = f2b(v.x); o.y = f2b(v.y); o.z = f2b(v.z); o.w = f2b(v.w);
            ((ushort4*)args.dst[0])[i] = o;
        }
    } else if (y == 1) {
        if (isbf) return;
        const int n1 = args.size[1] >> 2;
        const int n2 = args.size[2] >> 2;
        const int n3 = args.size[3] >> 2;
        const int n4 = args.size[4] >> 2;
        const int tot = n1 + n2 + n3 + n4;
        const int stride = 2048 * 256;
        for (int i = blockIdx.x * 256 + threadIdx.x; i < tot; i += stride) {
            const float4* s; ushort4* d; int j;
            if (i < n1)                { s = (const float4*)args.src[1]; d = (ushort4*)args.dst[1]; j = i; }
            else if (i < n1 + n2)      { s = (const float4*)args.src[2]; d = (ushort4*)args.dst[2]; j = i - n1; }
            else if (i < n1 + n2 + n3) { s = (const float4*)args.src[3]; d = (ushort4*)args.dst[3]; j = i - n1 - n2; }
            else                       { s = (const float4*)args.src[4]; d = (ushort4*)args.dst[4]; j = i - n1 - n2 - n3; }
            const float4 v = s[j];
            ushort4 o;
            o.x = f2b(v.x); o.y = f2b(v.y); o.z = f2b(v.z); o.w = f2b(v.w);
            d[j] = o;
        }
    } else {
        const int blk = blockIdx.x;
        if (blk < 896) {
            if (isbf) wec_body<true>(we_raw, wr_raw, cw_raw, wect, wrct);
            else      wec_body<false>(we_raw, wr_raw, cw_raw, wect, wrct);
        } else if (blk < 1024) {
            const int g = blk - 896;
            if (isbf) gather_lds_body<true>(args.src[0], xh, sx, g);
            else      gather_lds_body<false>(args.src[0], xh, sx, g);
        }
    }
}

// ---------------------------------------------------------------------------
// collapse unit (one 64-lane wave; body identical to the verified standalone
// collapse_kernel with blockIdx->blk, threadIdx->lane). NOW fused into gemm1:
// each gemm1 block's 4 waves compute the 4 units of ITS OWN bh and write
// we2t/wr2t[bh]. The 16 blocks sharing a bh write BIT-IDENTICAL bytes
// (deterministic same inputs), so concurrent duplicate writes are race-free,
// and each block reads back only bytes it wrote itself (own-L1/L2 fresh —
// no cross-XCD coherence dependency).
// ---------------------------------------------------------------------------
__device__ void collapse_unit(int blk, int lane,
                              const unsigned short* __restrict__ xh,
                              const unsigned short* __restrict__ wect,
                              const unsigned short* __restrict__ wrct,
                              unsigned short* __restrict__ we2t,
                              unsigned short* __restrict__ wr2t) {
    const int bh  = blk >> 2;
    const int qk  = (blk >> 1) & 1;
    const int dh  = blk & 1;
    const int h   = bh & 15;
    const int lq = lane >> 4;
    const int lm = lane & 15;

    const unsigned short* wsrc = (qk ? wrct : wect) + (size_t)h * HD * RP;
    const unsigned short* xsrc = xh + (size_t)bh * HD * RP;
    unsigned short* dst = (qk ? wr2t : we2t) + (size_t)bh * HD * HD;

    f32x4 acc[2][4];
    #pragma unroll
    for (int i = 0; i < 2; ++i)
        #pragma unroll
        for (int j = 0; j < 4; ++j) acc[i][j] = 0.f;

    for (int ks = 0; ks < RP / 32; ++ks) {
        bf16x8 a[2], bfr[4];
        #pragma unroll
        for (int rt = 0; rt < 2; ++rt)
            a[rt] = *(const bf16x8*)&wsrc[(size_t)(dh * 32 + rt * 16 + lm) * RP + ks * 32 + lq * 8];
        #pragma unroll
        for (int j = 0; j < 4; ++j)
            bfr[j] = *(const bf16x8*)&xsrc[(size_t)(j * 16 + lm) * RP + ks * 32 + lq * 8];
        #pragma unroll
        for (int rt = 0; rt < 2; ++rt)
            #pragma unroll
            for (int j = 0; j < 4; ++j)
                acc[rt][j] = __builtin_amdgcn_mfma_f32_16x16x32_bf16(
                    a[rt], bfr[j], acc[rt][j], 0, 0, 0);
    }

    #pragma unroll
    for (int rt = 0; rt < 2; ++rt)
        #pragma unroll
        for (int j = 0; j < 4; ++j)
            #pragma unroll
            for (int r = 0; r < 4; ++r) {
                const int dout = dh * 32 + rt * 16 + lq * 4 + r;
                const int din  = j * 16 + lm;
                dst[dout * HD + din] = f2b(acc[rt][j][r]);
            }
}

// ---------------------------------------------------------------------------
// Fused collapse + gemm1 + l2norm + score. Phase-1/2a/2b bodies identical to
// the verified round-6 kernel; NEW: per-block fused collapse between 2a and
// 2b (see collapse_unit comment). Dispatches drop 4 -> 3.
// ---------------------------------------------------------------------------
__global__ __launch_bounds__(256, 2)
void gemm1_score_kernel(const void* __restrict__ x_raw,
                        const void* __restrict__ qkw_raw,
                        const void* __restrict__ cwb_raw,
                        const unsigned short* __restrict__ xb,
                        const unsigned short* __restrict__ qkwb,
                        const unsigned short* __restrict__ cwbb,
                        const unsigned short* __restrict__ xh,
                        const unsigned short* __restrict__ wect,
                        const unsigned short* __restrict__ wrct,
                        unsigned short* __restrict__ we2t,
                        unsigned short* __restrict__ wr2t,
                        unsigned short* __restrict__ attn) {
    constexpr int QS = 72;
    __shared__ __align__(16) unsigned short pool[32768];  // 64 KB
    unsigned short* const AsBase = pool;          // 2 x 128x64 A tiles (32 KB)
    unsigned short* const BsBase = pool + 16384;  // 2 x 128x64 B tiles (32 KB)
    unsigned short* qn = pool;                    // phase 2: 128xQS
    unsigned short* kn = pool + 128 * QS;

    const bool isbf = detect_bf16((const unsigned int*)x_raw);
    const unsigned short* xs  = isbf ? (const unsigned short*)x_raw   : xb;
    const unsigned short* qks = isbf ? (const unsigned short*)qkw_raw : qkwb;
    const unsigned short* cwb = isbf ? (const unsigned short*)cwb_raw : cwbb;

    const int t    = threadIdx.x;
    const int wave = t >> 6;
    const int lane = t & 63;
    // XCD-chunked bijective swizzle (1024 blocks, 128 per XCD)
    const int lin     = blockIdx.y * 16 + blockIdx.x;
    const int logical = (lin & 7) * 128 + (lin >> 3);
    const int h       = logical & 15;
    const int mt      = logical >> 4;       // m-tile 0..63
    const int m0      = mt * 128;
    const int K       = C_;
    const int bh      = (mt >> 4) * H_ + h;

    const int srow  = lane >> 3;                    // 0..7
    const int sunit = (lane & 7) ^ srow;            // involutive swizzle
    const unsigned short* gA = xs + (size_t)(m0 + wave * 32 + srow) * K + sunit * 8;
    const int vb = wave * 32;                       // virtual B row 0..127
    const size_t brow = (vb < 64) ? (size_t)(h * HD + vb)
                                  : (size_t)(C_ + h * HD + (vb - 64));
    const unsigned short* gB = qks + (brow + srow) * K + sunit * 8;

    const int wr = (wave >> 1) * 64;        // row quadrant
    const int wc = (wave & 1) * 64;         // col quadrant: 0 = q, 64 = k
    const int lq = lane >> 4;
    const int lm = lane & 15;
    const int c0 = (lq ^ (lm & 7)) * 8;     // swizzled read col, ks=0

    f32x4 acc[4][4];
    #pragma unroll
    for (int i = 0; i < 4; ++i)
        #pragma unroll
        for (int j = 0; j < 4; ++j) acc[i][j] = 0.f;

    auto stage = [&](int buf) {
        unsigned short* dA = AsBase + buf * 8192 + wave * 2048;
        unsigned short* dB = BsBase + buf * 8192 + wave * 2048;
        #pragma unroll
        for (int i = 0; i < 4; ++i) {
            async_load16(gA + (size_t)i * 8 * K, dA + i * 512);
            async_load16(gB + (size_t)i * 8 * K, dB + i * 512);
        }
        gA += 64; gB += 64;
    };
    auto compute = [&](int buf) {
        const unsigned short* As = AsBase + buf * 8192;
        const unsigned short* Bs = BsBase + buf * 8192;
        #pragma unroll
        for (int ks = 0; ks < 2; ++ks) {
            const int cc = c0 ^ (ks * 32);
            bf16x8 af[4], bfr[4];
            #pragma unroll
            for (int i = 0; i < 4; ++i)
                af[i] = *(const bf16x8*)&As[(wr + i * 16 + lm) * 64 + cc];
            #pragma unroll
            for (int j = 0; j < 4; ++j)
                bfr[j] = *(const bf16x8*)&Bs[(wc + j * 16 + lm) * 64 + cc];
            #pragma unroll
            for (int i = 0; i < 4; ++i)
                #pragma unroll
                for (int j = 0; j < 4; ++j)
                    acc[i][j] = __builtin_amdgcn_mfma_f32_16x16x32_bf16(
                        af[i], bfr[j], acc[i][j], 0, 0, 0);
        }
    };

    constexpr int NTK = C_ / 64;   // 16 K-tiles
    stage(0);
    __syncthreads();
    for (int kt = 0; kt < NTK - 1; ++kt) {
        stage((kt + 1) & 1);       // prefetch next tile (other buffer)
        compute(kt & 1);           // 32 MFMA + 16 ds_read under the prefetch
        __syncthreads();           // drains vmcnt+lgkm: next tile ready, reads done
    }
    compute((NTK - 1) & 1);
    __syncthreads();               // before pool reuse by phase 2

    // ---- phase 2a: per-row l2 norm + scaled bf16 store to LDS ----
    unsigned short* dst = (wc == 0) ? qn : kn;
    #pragma unroll
    for (int i = 0; i < 4; ++i) {
        float inv[4];
        #pragma unroll
        for (int r = 0; r < 4; ++r) {
            float s = 0.f;
            #pragma unroll
            for (int j = 0; j < 4; ++j) s += acc[i][j][r] * acc[i][j][r];
            s += __shfl_xor(s, 1, 64);
            s += __shfl_xor(s, 2, 64);
            s += __shfl_xor(s, 4, 64);
            s += __shfl_xor(s, 8, 64);
            inv[r] = 1.f / fmaxf(sqrtf(s), 1e-12f);
        }
        #pragma unroll
        for (int j = 0; j < 4; ++j)
            #pragma unroll
            for (int r = 0; r < 4; ++r) {
                const int row = wr + i * 16 + lq * 4 + r;
                dst[row * QS + j * 16 + lm] = f2b(acc[i][j][r] * inv[r]);
            }
    }

    // ---- fused collapse: wave w computes unit (bh, qk=w>>1, dh=w&1) ----
    collapse_unit(bh * 4 + wave, lane, xh, wect, wrct, we2t, wr2t);

    __syncthreads();   // drains vmcnt (collapse writes done) + lgkm; qn/kn ready

    // ---- phase 2b: attn = qn@We2T^T + kn@Wr2T^T + cw_b ----
    const unsigned short* wq = we2t + (size_t)bh * HD * HD;
    const unsigned short* wk = wr2t + (size_t)bh * HD * HD;

    bf16x8 bq[2][4], bk[2][4];
    #pragma unroll
    for (int t2 = 0; t2 < 2; ++t2)
        #pragma unroll
        for (int j = 0; j < 4; ++j) {
            const int dout = j * 16 + lm;
            bq[t2][j] = *(const bf16x8*)&wq[dout * HD + t2 * 32 + lq * 8];
            bk[t2][j] = *(const bf16x8*)&wk[dout * HD + t2 * 32 + lq * 8];
        }

    f32x4 accS[2][4];
    #pragma unroll
    for (int rt = 0; rt < 2; ++rt)
        #pragma unroll
        for (int j = 0; j < 4; ++j) accS[rt][j] = 0.f;

    #pragma unroll
    for (int rt = 0; rt < 2; ++rt) {
        const int lr = wave * 32 + rt * 16 + lm;
        bf16x8 aq0 = *(const bf16x8*)&qn[lr * QS + lq * 8];
        bf16x8 aq1 = *(const bf16x8*)&qn[lr * QS + 32 + lq * 8];
        bf16x8 ak0 = *(const bf16x8*)&kn[lr * QS + lq * 8];
        bf16x8 ak1 = *(const bf16x8*)&kn[lr * QS + 32 + lq * 8];
        #pragma unroll
        for (int j = 0; j < 4; ++j) {
            accS[rt][j] = __builtin_amdgcn_mfma_f32_16x16x32_bf16(aq0, bq[0][j], accS[rt][j], 0, 0, 0);
            accS[rt][j] = __builtin_amdgcn_mfma_f32_16x16x32_bf16(aq1, bq[1][j], accS[rt][j], 0, 0, 0);
            accS[rt][j] = __builtin_amdgcn_mfma_f32_16x16x32_bf16(ak0, bk[0][j], accS[rt][j], 0, 0, 0);
            accS[rt][j] = __builtin_amdgcn_mfma_f32_16x16x32_bf16(ak1, bk[1][j], accS[rt][j], 0, 0, 0);
        }
    }

    #pragma unroll
    for (int rt = 0; rt < 2; ++rt)
        #pragma unroll
        for (int j = 0; j < 4; ++j) {
            const int dout = j * 16 + lm;
            const float bv = b2f_raw(cwb[dout]);
            #pragma unroll
            for (int r = 0; r < 4; ++r) {
                const int row = m0 + wave * 32 + rt * 16 + lq * 4 + r;
                attn[(size_t)row * C_ + h * HD + dout] = f2b(accS[rt][j][r] + bv);
            }
        }
}

// ---------------------------------------------------------------------------
// Output projection (unchanged from round 6 — verified).
// ---------------------------------------------------------------------------
template <bool OBF>
__device__ void mfma_gemm_body64(const unsigned short* __restrict__ A,
                                 const unsigned short* __restrict__ W,
                                 const unsigned short* __restrict__ bias,
                                 void* __restrict__ out,
                                 int M, int N, int K, int m0, int n0) {
    __shared__ __align__(16) unsigned short AsBase[16384];  // 2 x 128x64
    __shared__ __align__(16) unsigned short BsBase[16384];  // 2 x 128x64 (64 KB)

    const int t    = threadIdx.x;
    const int wave = t >> 6;
    const int lane = t & 63;

    const int srow  = lane >> 3;
    const int sunit = (lane & 7) ^ srow;
    const unsigned short* gA = A + (size_t)(m0 + wave * 32 + srow) * K + sunit * 8;
    const unsigned short* gB = W + (size_t)(n0 + wave * 32 + srow) * K + sunit * 8;

    const int wr = (wave >> 1) * 64;
    const int wc = (wave & 1) * 64;
    const int lq = lane >> 4;
    const int lm = lane & 15;
    const int c0 = (lq ^ (lm & 7)) * 8;

    f32x4 acc[4][4];
    #pragma unroll
    for (int i = 0; i < 4; ++i)
        #pragma unroll
        for (int j = 0; j < 4; ++j) acc[i][j] = 0.f;

    auto stage = [&](int buf) {
        unsigned short* dA = AsBase + buf * 8192 + wave * 2048;
        unsigned short* dB = BsBase + buf * 8192 + wave * 2048;
        #pragma unroll
        for (int i = 0; i < 4; ++i) {
            async_load16(gA + (size_t)i * 8 * K, dA + i * 512);
            async_load16(gB + (size_t)i * 8 * K, dB + i * 512);
        }
        gA += 64; gB += 64;
    };
    auto compute = [&](int buf) {
        const unsigned short* As = AsBase + buf * 8192;
        const unsigned short* Bs = BsBase + buf * 8192;
        #pragma unroll
        for (int ks = 0; ks < 2; ++ks) {
            const int cc = c0 ^ (ks * 32);
            bf16x8 af[4], bfr[4];
            #pragma unroll
            for (int i = 0; i < 4; ++i)
                af[i] = *(const bf16x8*)&As[(wr + i * 16 + lm) * 64 + cc];
            #pragma unroll
            for (int j = 0; j < 4; ++j)
                bfr[j] = *(const bf16x8*)&Bs[(wc + j * 16 + lm) * 64 + cc];
            #pragma unroll
            for (int i = 0; i < 4; ++i)
                #pragma unroll
                for (int j = 0; j < 4; ++j)
                    acc[i][j] = __builtin_amdgcn_mfma_f32_16x16x32_bf16(
                        af[i], bfr[j], acc[i][j], 0, 0, 0);
        }
    };

    const int NTK = K / 64;   // 16
    stage(0);
    __syncthreads();
    for (int kt = 0; kt < NTK - 1; ++kt) {
        stage((kt + 1) & 1);
        compute(kt & 1);
        __syncthreads();
    }
    compute((NTK - 1) & 1);
    // epilogue is register-only: no trailing barrier needed

    #pragma unroll
    for (int i = 0; i < 4; ++i) {
        #pragma unroll
        for (int j = 0; j < 4; ++j) {
            const int col = n0 + wc + j * 16 + lm;
            const float bv = b2f_raw(bias[col]);
            #pragma unroll
            for (int r = 0; r < 4; ++r) {
                const int row = m0 + wr + i * 16 + lq * 4 + r;
                const float v = acc[i][j][r] + bv;
                if constexpr (OBF)
                    ((__hip_bfloat16*)out)[(size_t)row * N + col] = __float2bfloat16(v);
                else
                    ((float*)out)[(size_t)row * N + col] = v;
            }
        }
    }
}

__global__ __launch_bounds__(256, 2)
void gemm2_kernel(const void* __restrict__ x_raw,
                  const void* __restrict__ pw_raw,
                  const void* __restrict__ pb_raw,
                  const unsigned short* __restrict__ attn,
                  const unsigned short* __restrict__ pwb,
                  const unsigned short* __restrict__ pbb,
                  void* __restrict__ out) {
    const bool isbf = detect_bf16((const unsigned int*)x_raw);
    const unsigned short* W = isbf ? (const unsigned short*)pw_raw : pwb;
    const unsigned short* bias = isbf ? (const unsigned short*)pb_raw : pbb;
    // XCD-chunked bijective swizzle (512 blocks, 64 per XCD)
    const int lin     = blockIdx.y * 8 + blockIdx.x;
    const int logical = (lin & 7) * 64 + (lin >> 3);
    const int n0      = (logical & 7) * 128;
    const int m0      = (logical >> 3) * 128;
    if (isbf) mfma_gemm_body64<true>(attn, W, bias, out, B_ * N_, C_, C_, m0, n0);
    else      mfma_gemm_body64<false>(attn, W, bias, out, B_ * N_, C_, C_, m0, n0);
}

// ---------------------------------------------------------------------------
// 3 dispatches: prep(convert+wec+gather) -> gemm1(+fused collapse) -> gemm2.
// ws high-water ~44 MB (< proven-safe 57.9 MB).
// ---------------------------------------------------------------------------
extern "C" void kernel_launch(void* const* d_in, const int* in_sizes, int n_in,
                              void* d_out, int out_size, void* d_ws, size_t ws_size,
                              hipStream_t stream) {
    (void)in_sizes; (void)n_in; (void)out_size; (void)ws_size;

    char* ws = (char*)d_ws;
    size_t off = 0;
    auto alloc = [&](size_t bytes) {
        char* p = ws + off;
        off += (bytes + 255) & ~(size_t)255;
        return p;
    };

    unsigned short* xb    = (unsigned short*)alloc((size_t)B_ * N_ * C_ * 2);   // 16.78 MB
    unsigned short* qkwb  = (unsigned short*)alloc((size_t)2 * C_ * C_ * 2);    // 4.19 MB
    unsigned short* pwb   = (unsigned short*)alloc((size_t)C_ * C_ * 2);        // 2.10 MB
    unsigned short* pbb   = (unsigned short*)alloc((size_t)C_ * 2);
    unsigned short* cwbb  = (unsigned short*)alloc((size_t)HD * 2);
    unsigned short* attn  = (unsigned short*)alloc((size_t)B_ * N_ * C_ * 2);   // 16.78 MB
    unsigned short* we2t  = (unsigned short*)alloc((size_t)B_ * H_ * HD * HD * 2);
    unsigned short* wr2t  = (unsigned short*)alloc((size_t)B_ * H_ * HD * HD * 2);
    unsigned short* wect  = (unsigned short*)alloc((size_t)H_ * HD * RP * 2);
    unsigned short* wrct  = (unsigned short*)alloc((size_t)H_ * HD * RP * 2);
    unsigned short* xh    = (unsigned short*)alloc((size_t)B_ * H_ * HD * RP * 2);

    const int M = B_ * N_;  // 8192

    // 1) prep: converts (skipped for bf16) + wec + gather
    CvtArgs ca;
    ca.src[0] = d_in[0]; ca.dst[0] = xb;   ca.size[0] = B_ * N_ * C_;
    ca.src[1] = d_in[1]; ca.dst[1] = qkwb; ca.size[1] = 2 * C_ * C_;
    ca.src[2] = d_in[2]; ca.dst[2] = pwb;  ca.size[2] = C_ * C_;
    ca.src[3] = d_in[3]; ca.dst[3] = pbb;  ca.size[3] = C_;
    ca.src[4] = d_in[7]; ca.dst[4] = cwbb; ca.size[4] = HD;
    fused_prep_kernel<<<dim3(2048, 3), 256, 0, stream>>>(
        ca, d_in[4], d_in[5], d_in[6], wect, wrct, xh);

    // 2) fused collapse + qk-projection + l2norm + score -> attn
    gemm1_score_kernel<<<dim3(16, M / 128), 256, 0, stream>>>(
        d_in[0], d_in[1], d_in[7], xb, qkwb, cwbb,
        xh, wect, wrct, we2t, wr2t, attn);

    // 3) output projection: out = attn @ proj_w^T + proj_b
    gemm2_kernel<<<dim3(C_ / 128, M / 128), 256, 0, stream>>>(
        d_in[0], d_in[2], d_in[3], attn, pwb, pbb, d_out);
}